// Round 7
// baseline (136.036 us; speedup 1.0000x reference)
//
#include <hip/hip_runtime.h>
#include <hip/hip_bf16.h>

#define BATCH 1024
#define NA 32
#define UD 64
#define HID 128

typedef _Float16 f16x8 __attribute__((ext_vector_type(8)));
typedef float f32x4 __attribute__((ext_vector_type(4)));
typedef float f32x16 __attribute__((ext_vector_type(16)));

// ---------------------------------------------------------------------------
// Prep kernel: W1/W2 -> f16 MFMA fragments in ws (64 KB).
//  units 0..31 : W2 frags for 32x32x16, unit = m*8+ks (m 0..3, ks 0..7):
//                lane holds A[h=m*32+(lane&31)][k=ks*16+(lane>>5)*8+e] = W2[k][h]
//  units 32..63: W1 frags for 16x16x32, u = h*16+ks*8+nt:
//                lane holds W1[h*64+ks*32+(lane>>4)*8+e][nt*16+(lane&15)]
// ---------------------------------------------------------------------------
__global__ void prep_weights(const float* __restrict__ W1,
                             const float* __restrict__ W2,
                             _Float16* __restrict__ ws)
{
    int tid  = blockIdx.x * blockDim.x + threadIdx.x;  // 0..4095
    int unit = tid >> 6;
    int lane = tid & 63;
    f16x8 v;
    if (unit < 32) {
        int m  = unit >> 3, ks = unit & 7;
        int h  = m * 32 + (lane & 31);
        int k0 = ks * 16 + (lane >> 5) * 8;
        #pragma unroll
        for (int e = 0; e < 8; ++e)
            v[e] = (_Float16)W2[(k0 + e) * HID + h];
    } else {
        int u = unit - 32;
        int hh = u >> 4, ks = (u >> 3) & 1, nt = u & 7;
        int col = nt * 16 + (lane & 15);
        int k0  = ks * 32 + (lane >> 4) * 8;
        #pragma unroll
        for (int e = 0; e < 8; ++e)
            v[e] = (_Float16)W1[(hh * UD + k0 + e) * HID + col];
    }
    *(f16x8*)&ws[(size_t)(unit * 64 + lane) * 8] = v;
}

// ---------------------------------------------------------------------------
// Main kernel: one block per batch element, 256 threads = 4 waves.
// Phase A (16x16x32): hi = us@W1[:64]+b1, hj = us@W1[64:] -> f16 LDS, swizzled.
// Phase B (32x32x16, hidden-split): wave w owns hidden quarter m=w; its 8 W2
//   frags + lane's hj row + b2/w3 quarter in REGISTERS. Per i: 8 broadcast
//   ds_reads of hi[i], 8 MFMAs in TWO independent chains (even/odd ks) to
//   halve dependency latency, partial p -> pw LDS; final convergent pass.
// __launch_bounds__(256,4): 4 blocks/CU (LDS 36.9KB x4 fits; VGPR <= 128).
// ---------------------------------------------------------------------------
__global__ __launch_bounds__(256, 4)
void graph_learner_kernel(const float* __restrict__ us_g,
                          const float* __restrict__ b1,
                          const float* __restrict__ b2,
                          const float* __restrict__ W3,
                          const float* __restrict__ b3,
                          const _Float16* __restrict__ ws,
                          float* __restrict__ out)
{
    __shared__ _Float16 us_f16[NA * UD]  __attribute__((aligned(16)));  // 4 KB
    __shared__ _Float16 hi_lds[NA * HID] __attribute__((aligned(16)));  // 8 KB
    __shared__ _Float16 hj_lds[NA * HID] __attribute__((aligned(16)));  // 8 KB
    __shared__ float    pw_lds[NA * NA * 4] __attribute__((aligned(16))); // 16 KB

    const int b    = blockIdx.x;
    const int t    = threadIdx.x;
    const int w    = t >> 6;        // wave 0..3 = hidden quarter
    const int lane = t & 63;
    const int l15  = lane & 15;
    const int lq   = lane >> 4;
    const int l31  = lane & 31;
    const int hi2  = lane >> 5;     // 0/1

    // ---- stage unit_states[:, b, :] -> us_f16 (chunk-swizzled)
    {
        int i  = t >> 3;            // agent 0..31
        int c  = t & 7;             // 8-half chunk
        const float* src = us_g + ((size_t)i * BATCH + (size_t)b) * UD + c * 8;
        float4 va = *(const float4*)src;
        float4 vb = *(const float4*)(src + 4);
        f16x8 v8;
        v8[0] = (_Float16)va.x; v8[1] = (_Float16)va.y;
        v8[2] = (_Float16)va.z; v8[3] = (_Float16)va.w;
        v8[4] = (_Float16)vb.x; v8[5] = (_Float16)vb.y;
        v8[6] = (_Float16)vb.z; v8[7] = (_Float16)vb.w;
        *(f16x8*)&us_f16[i * UD + ((c ^ (i & 7)) << 3)] = v8;
    }

    // ---- per-wave quarter params (C/D row r -> hidden (r&3)+8*(r>>2)+4*hi2)
    float b2q[16], w3q[16];
    #pragma unroll
    for (int g = 0; g < 4; ++g) {
        f32x4 vb2 = *(const f32x4*)&b2[w * 32 + g * 8 + hi2 * 4];
        f32x4 vw3 = *(const f32x4*)&W3[w * 32 + g * 8 + hi2 * 4];
        #pragma unroll
        for (int s = 0; s < 4; ++s) {
            b2q[g * 4 + s] = vb2[s];
            w3q[g * 4 + s] = vw3[s];
        }
    }
    const float b3s = b3[0];

    // ---- W2 fragments for this wave's quarter: 8 frags = 32 VGPRs
    f16x8 w2f[8];
    #pragma unroll
    for (int ks = 0; ks < 8; ++ks)
        w2f[ks] = *(const f16x8*)&ws[(size_t)((w * 8 + ks) * 64 + lane) * 8];

    // ---- phase-A weights (16x16x32 layout from ws)
    const int Mt = w >> 1;
    const int nh = w & 1;
    f16x8 w1f[4][2][2];
    float b1v[4];
    #pragma unroll
    for (int n = 0; n < 4; ++n) {
        int nt = nh * 4 + n;
        b1v[n] = b1[nt * 16 + l15];
        #pragma unroll
        for (int h = 0; h < 2; ++h)
            #pragma unroll
            for (int ks = 0; ks < 2; ++ks) {
                int u = 32 + h * 16 + ks * 8 + nt;
                w1f[n][h][ks] = *(const f16x8*)&ws[(size_t)(u * 64 + lane) * 8];
            }
    }

    __syncthreads();

    // ---- phase A: 16 MFMAs/wave (16x16x32); hi gets b1 via C-init
    {
        f16x8 af[2];
        #pragma unroll
        for (int ks = 0; ks < 2; ++ks) {
            int row = Mt * 16 + l15;
            int c   = ks * 4 + lq;
            af[ks] = *(const f16x8*)&us_f16[row * UD + ((c ^ (row & 7)) << 3)];
        }
        #pragma unroll
        for (int n = 0; n < 4; ++n) {
            int nt = nh * 4 + n;
            f32x4 ahi = {b1v[n], b1v[n], b1v[n], b1v[n]};
            f32x4 ahj = {0.f, 0.f, 0.f, 0.f};
            #pragma unroll
            for (int ks = 0; ks < 2; ++ks) {
                ahi = __builtin_amdgcn_mfma_f32_16x16x32_f16(af[ks], w1f[n][0][ks], ahi, 0, 0, 0);
                ahj = __builtin_amdgcn_mfma_f32_16x16x32_f16(af[ks], w1f[n][1][ks], ahj, 0, 0, 0);
            }
            #pragma unroll
            for (int r = 0; r < 4; ++r) {
                int row = Mt * 16 + lq * 4 + r;
                int col = nt * 16 + l15;
                int idx = row * HID + ((((col >> 3) ^ (row & 15)) << 3) + (col & 7));
                hi_lds[idx] = (_Float16)ahi[r];
                hj_lds[idx] = (_Float16)ahj[r];
            }
        }
    }

    __syncthreads();

    // ---- hj row for this lane -> registers
    f16x8 g8[8];
    #pragma unroll
    for (int ks = 0; ks < 8; ++ks) {
        int c = ks * 2 + hi2;
        g8[ks] = *(const f16x8*)&hj_lds[l31 * HID + ((c ^ (l31 & 15)) << 3)];
    }

    // ---- phase B: sweep all 32 i; two independent MFMA chains per i
    #pragma unroll 1
    for (int i = 0; i < 32; ++i) {
        const int isz = i & 15;
        const _Float16* hir = &hi_lds[i * HID];

        f16x8 h8[8];
        #pragma unroll
        for (int ks = 0; ks < 8; ++ks) {
            int c = ks * 2 + hi2;
            h8[ks] = *(const f16x8*)&hir[(c ^ isz) << 3];   // broadcast read
        }

        f32x16 accE, accO;
        {
            f16x8 z = {};
            f16x8 s0 = h8[0] + g8[0];
            f16x8 x0 = __builtin_elementwise_max(s0, z);
            f32x16 cE;
            #pragma unroll
            for (int r = 0; r < 16; ++r) cE[r] = b2q[r];
            accE = __builtin_amdgcn_mfma_f32_32x32x16_f16(w2f[0], x0, cE, 0, 0, 0);

            f16x8 s1 = h8[1] + g8[1];
            f16x8 x1 = __builtin_elementwise_max(s1, z);
            f32x16 cO = {};
            accO = __builtin_amdgcn_mfma_f32_32x32x16_f16(w2f[1], x1, cO, 0, 0, 0);

            #pragma unroll
            for (int ks = 2; ks < 8; ks += 2) {
                f16x8 sE = h8[ks] + g8[ks];
                f16x8 xE = __builtin_elementwise_max(sE, z);
                accE = __builtin_amdgcn_mfma_f32_32x32x16_f16(w2f[ks], xE, accE, 0, 0, 0);
                f16x8 sO = h8[ks + 1] + g8[ks + 1];
                f16x8 xO = __builtin_elementwise_max(sO, z);
                accO = __builtin_amdgcn_mfma_f32_32x32x16_f16(w2f[ks + 1], xO, accO, 0, 0, 0);
            }
        }

        // partial layer-3 over this wave's 32 hidden (merge chains here)
        float p = 0.f;
        #pragma unroll
        for (int r = 0; r < 16; ++r)
            p += fmaxf(accE[r] + accO[r], 0.f) * w3q[r];
        p += __shfl_xor(p, 32);
        if (lane < 32)
            pw_lds[(i * 32 + l31) * 4 + w] = p;
    }

    __syncthreads();

    // ---- final: thread t handles pairs {t, t+256, t+512, t+768}
    #pragma unroll
    for (int q = 0; q < 4; ++q) {
        int p = q * 256 + t;
        f32x4 v = *(const f32x4*)&pw_lds[p * 4];
        float x  = v[0] + v[1] + v[2] + v[3] + b3s;
        float sg = 1.f / (1.f + __expf(-x));
        if ((p >> 5) == (p & 31)) sg += 1.f;
        out[(size_t)b * (NA * NA) + p] = sg;
    }
}

extern "C" void kernel_launch(void* const* d_in, const int* in_sizes, int n_in,
                              void* d_out, int out_size, void* d_ws, size_t ws_size,
                              hipStream_t stream) {
    // inputs: 0=state (unused), 1=unit_states, 2=W1, 3=b1, 4=W2, 5=b2, 6=W3, 7=b3
    const float* us = (const float*)d_in[1];
    const float* W1 = (const float*)d_in[2];
    const float* b1 = (const float*)d_in[3];
    const float* W2 = (const float*)d_in[4];
    const float* b2 = (const float*)d_in[5];
    const float* W3 = (const float*)d_in[6];
    const float* b3 = (const float*)d_in[7];
    float* out = (float*)d_out;
    _Float16* ws = (_Float16*)d_ws;

    prep_weights<<<dim3(16), dim3(256), 0, stream>>>(W1, W2, ws);
    graph_learner_kernel<<<dim3(BATCH), dim3(256), 0, stream>>>(
        us, b1, b2, W3, b3, ws, out);
}

// Round 10
// 116.419 us; speedup vs baseline: 1.1685x; 1.1685x over previous
//
#include <hip/hip_runtime.h>
#include <hip/hip_bf16.h>

#define BATCH 1024
#define NA 32
#define UD 64
#define HID 128

typedef _Float16 f16x8 __attribute__((ext_vector_type(8)));
typedef float f32x4 __attribute__((ext_vector_type(4)));
typedef float f32x16 __attribute__((ext_vector_type(16)));

// ---------------------------------------------------------------------------
// Prep kernel: W1/W2 -> f16 MFMA fragments in ws (64 KB).
//  units 0..31 : W2 frags for 32x32x16, unit = m*8+ks (m 0..3, ks 0..7):
//                lane holds A[h=m*32+(lane&31)][k=ks*16+(lane>>5)*8+e] = W2[k][h]
//  units 32..63: W1 frags for 16x16x32, u = h*16+ks*8+nt:
//                lane holds W1[h*64+ks*32+(lane>>4)*8+e][nt*16+(lane&15)]
// ---------------------------------------------------------------------------
__global__ void prep_weights(const float* __restrict__ W1,
                             const float* __restrict__ W2,
                             _Float16* __restrict__ ws)
{
    int tid  = blockIdx.x * blockDim.x + threadIdx.x;  // 0..4095
    int unit = tid >> 6;
    int lane = tid & 63;
    f16x8 v;
    if (unit < 32) {
        int m  = unit >> 3, ks = unit & 7;
        int h  = m * 32 + (lane & 31);
        int k0 = ks * 16 + (lane >> 5) * 8;
        #pragma unroll
        for (int e = 0; e < 8; ++e)
            v[e] = (_Float16)W2[(k0 + e) * HID + h];
    } else {
        int u = unit - 32;
        int hh = u >> 4, ks = (u >> 3) & 1, nt = u & 7;
        int col = nt * 16 + (lane & 15);
        int k0  = ks * 32 + (lane >> 4) * 8;
        #pragma unroll
        for (int e = 0; e < 8; ++e)
            v[e] = (_Float16)W1[(hh * UD + k0 + e) * HID + col];
    }
    *(f16x8*)&ws[(size_t)(unit * 64 + lane) * 8] = v;
}

// ---------------------------------------------------------------------------
// Main kernel: one block per batch element, 256 threads = 4 waves.
// Phase A (16x16x32): hi = us@W1[:64]+b1, hj = us@W1[64:] -> f16 LDS, swizzled.
// Phase B (32x32x16, hidden-split): wave w owns hidden quarter m=w; its 8 W2
//   frags + lane's hj row + b2 quarter in REGISTERS; w3 quarter in LDS
//   (broadcast reads in epilogue) to cut persistent regs. Per i: 8 broadcast
//   ds_reads of hi[i], 8 MFMAs in TWO independent chains, partial p -> pw LDS.
// __launch_bounds__(256,3): 3 blocks/CU (LDS 37KB x3 fits; ~168-reg budget
// covers the ~144-reg demand WITHOUT scratch spills -- R7's failure mode).
// ---------------------------------------------------------------------------
__global__ __launch_bounds__(256, 3)
void graph_learner_kernel(const float* __restrict__ us_g,
                          const float* __restrict__ b1,
                          const float* __restrict__ b2,
                          const float* __restrict__ W3,
                          const float* __restrict__ b3,
                          const _Float16* __restrict__ ws,
                          float* __restrict__ out)
{
    __shared__ _Float16 us_f16[NA * UD]  __attribute__((aligned(16)));  // 4 KB
    __shared__ _Float16 hi_lds[NA * HID] __attribute__((aligned(16)));  // 8 KB
    __shared__ _Float16 hj_lds[NA * HID] __attribute__((aligned(16)));  // 8 KB
    __shared__ float    pw_lds[NA * NA * 4] __attribute__((aligned(16))); // 16 KB
    __shared__ float    w3_lds[HID] __attribute__((aligned(16)));       // 0.5 KB

    const int b    = blockIdx.x;
    const int t    = threadIdx.x;
    const int w    = t >> 6;        // wave 0..3 = hidden quarter
    const int lane = t & 63;
    const int l15  = lane & 15;
    const int lq   = lane >> 4;
    const int l31  = lane & 31;
    const int hi2  = lane >> 5;     // 0/1

    // ---- stage unit_states[:, b, :] -> us_f16 (chunk-swizzled)
    {
        int i  = t >> 3;            // agent 0..31
        int c  = t & 7;             // 8-half chunk
        const float* src = us_g + ((size_t)i * BATCH + (size_t)b) * UD + c * 8;
        float4 va = *(const float4*)src;
        float4 vb = *(const float4*)(src + 4);
        f16x8 v8;
        v8[0] = (_Float16)va.x; v8[1] = (_Float16)va.y;
        v8[2] = (_Float16)va.z; v8[3] = (_Float16)va.w;
        v8[4] = (_Float16)vb.x; v8[5] = (_Float16)vb.y;
        v8[6] = (_Float16)vb.z; v8[7] = (_Float16)vb.w;
        *(f16x8*)&us_f16[i * UD + ((c ^ (i & 7)) << 3)] = v8;
    }
    // ---- stage w3 -> LDS
    if (t < 32)
        *(f32x4*)&w3_lds[t * 4] = *(const f32x4*)&W3[t * 4];

    // ---- per-wave quarter b2 (C/D row r -> hidden (r&3)+8*(r>>2)+4*hi2)
    float b2q[16];
    #pragma unroll
    for (int g = 0; g < 4; ++g) {
        f32x4 vb2 = *(const f32x4*)&b2[w * 32 + g * 8 + hi2 * 4];
        #pragma unroll
        for (int s = 0; s < 4; ++s)
            b2q[g * 4 + s] = vb2[s];
    }
    const float b3s = b3[0];

    // ---- W2 fragments for this wave's quarter: 8 frags = 32 VGPRs
    f16x8 w2f[8];
    #pragma unroll
    for (int ks = 0; ks < 8; ++ks)
        w2f[ks] = *(const f16x8*)&ws[(size_t)((w * 8 + ks) * 64 + lane) * 8];

    // ---- phase-A weights (16x16x32 layout from ws)
    const int Mt = w >> 1;
    const int nh = w & 1;
    f16x8 w1f[4][2][2];
    float b1v[4];
    #pragma unroll
    for (int n = 0; n < 4; ++n) {
        int nt = nh * 4 + n;
        b1v[n] = b1[nt * 16 + l15];
        #pragma unroll
        for (int h = 0; h < 2; ++h)
            #pragma unroll
            for (int ks = 0; ks < 2; ++ks) {
                int u = 32 + h * 16 + ks * 8 + nt;
                w1f[n][h][ks] = *(const f16x8*)&ws[(size_t)(u * 64 + lane) * 8];
            }
    }

    __syncthreads();

    // ---- phase A: 16 MFMAs/wave (16x16x32); hi gets b1 via C-init
    {
        f16x8 af[2];
        #pragma unroll
        for (int ks = 0; ks < 2; ++ks) {
            int row = Mt * 16 + l15;
            int c   = ks * 4 + lq;
            af[ks] = *(const f16x8*)&us_f16[row * UD + ((c ^ (row & 7)) << 3)];
        }
        #pragma unroll
        for (int n = 0; n < 4; ++n) {
            int nt = nh * 4 + n;
            f32x4 ahi = {b1v[n], b1v[n], b1v[n], b1v[n]};
            f32x4 ahj = {0.f, 0.f, 0.f, 0.f};
            #pragma unroll
            for (int ks = 0; ks < 2; ++ks) {
                ahi = __builtin_amdgcn_mfma_f32_16x16x32_f16(af[ks], w1f[n][0][ks], ahi, 0, 0, 0);
                ahj = __builtin_amdgcn_mfma_f32_16x16x32_f16(af[ks], w1f[n][1][ks], ahj, 0, 0, 0);
            }
            #pragma unroll
            for (int r = 0; r < 4; ++r) {
                int row = Mt * 16 + lq * 4 + r;
                int col = nt * 16 + l15;
                int idx = row * HID + ((((col >> 3) ^ (row & 15)) << 3) + (col & 7));
                hi_lds[idx] = (_Float16)ahi[r];
                hj_lds[idx] = (_Float16)ahj[r];
            }
        }
    }

    __syncthreads();

    // ---- hj row for this lane -> registers
    f16x8 g8[8];
    #pragma unroll
    for (int ks = 0; ks < 8; ++ks) {
        int c = ks * 2 + hi2;
        g8[ks] = *(const f16x8*)&hj_lds[l31 * HID + ((c ^ (l31 & 15)) << 3)];
    }

    // ---- phase B: sweep all 32 i; two independent MFMA chains per i
    #pragma unroll 1
    for (int i = 0; i < 32; ++i) {
        const int isz = i & 15;
        const _Float16* hir = &hi_lds[i * HID];

        f16x8 h8[8];
        #pragma unroll
        for (int ks = 0; ks < 8; ++ks) {
            int c = ks * 2 + hi2;
            h8[ks] = *(const f16x8*)&hir[(c ^ isz) << 3];   // broadcast read
        }

        f32x16 accE, accO;
        {
            f16x8 z = {};
            f16x8 s0 = h8[0] + g8[0];
            f16x8 x0 = __builtin_elementwise_max(s0, z);
            f32x16 cE;
            #pragma unroll
            for (int r = 0; r < 16; ++r) cE[r] = b2q[r];
            accE = __builtin_amdgcn_mfma_f32_32x32x16_f16(w2f[0], x0, cE, 0, 0, 0);

            f16x8 s1 = h8[1] + g8[1];
            f16x8 x1 = __builtin_elementwise_max(s1, z);
            f32x16 cO = {};
            accO = __builtin_amdgcn_mfma_f32_32x32x16_f16(w2f[1], x1, cO, 0, 0, 0);

            #pragma unroll
            for (int ks = 2; ks < 8; ks += 2) {
                f16x8 sE = h8[ks] + g8[ks];
                f16x8 xE = __builtin_elementwise_max(sE, z);
                accE = __builtin_amdgcn_mfma_f32_32x32x16_f16(w2f[ks], xE, accE, 0, 0, 0);
                f16x8 sO = h8[ks + 1] + g8[ks + 1];
                f16x8 xO = __builtin_elementwise_max(sO, z);
                accO = __builtin_amdgcn_mfma_f32_32x32x16_f16(w2f[ks + 1], xO, accO, 0, 0, 0);
            }
        }

        // partial layer-3 over this wave's 32 hidden; w3 via broadcast LDS reads
        float p = 0.f;
        #pragma unroll
        for (int g = 0; g < 4; ++g) {
            f32x4 w3v = *(const f32x4*)&w3_lds[w * 32 + g * 8 + hi2 * 4];
            #pragma unroll
            for (int s = 0; s < 4; ++s)
                p += fmaxf(accE[g * 4 + s] + accO[g * 4 + s], 0.f) * w3v[s];
        }
        p += __shfl_xor(p, 32);
        if (lane < 32)
            pw_lds[(i * 32 + l31) * 4 + w] = p;
    }

    __syncthreads();

    // ---- final: thread t handles pairs {t, t+256, t+512, t+768}
    #pragma unroll
    for (int q = 0; q < 4; ++q) {
        int p = q * 256 + t;
        f32x4 v = *(const f32x4*)&pw_lds[p * 4];
        float x  = v[0] + v[1] + v[2] + v[3] + b3s;
        float sg = 1.f / (1.f + __expf(-x));
        if ((p >> 5) == (p & 31)) sg += 1.f;
        out[(size_t)b * (NA * NA) + p] = sg;
    }
}

extern "C" void kernel_launch(void* const* d_in, const int* in_sizes, int n_in,
                              void* d_out, int out_size, void* d_ws, size_t ws_size,
                              hipStream_t stream) {
    // inputs: 0=state (unused), 1=unit_states, 2=W1, 3=b1, 4=W2, 5=b2, 6=W3, 7=b3
    const float* us = (const float*)d_in[1];
    const float* W1 = (const float*)d_in[2];
    const float* b1 = (const float*)d_in[3];
    const float* W2 = (const float*)d_in[4];
    const float* b2 = (const float*)d_in[5];
    const float* W3 = (const float*)d_in[6];
    const float* b3 = (const float*)d_in[7];
    float* out = (float*)d_out;
    _Float16* ws = (_Float16*)d_ws;

    prep_weights<<<dim3(16), dim3(256), 0, stream>>>(W1, W2, ws);
    graph_learner_kernel<<<dim3(BATCH), dim3(256), 0, stream>>>(
        us, b1, b2, W3, b3, ws, out);
}